// Round 2
// baseline (168.016 us; speedup 1.0000x reference)
//
#include <hip/hip_runtime.h>

#define SEQ 512
#define HID 768
#define P2  46
#define BLK 256
#define KH  384        // half of K
#define WST 392        // LDS W row stride in shorts (196 dwords == 4 mod 32 -> uniform banks)

typedef short bf16x8 __attribute__((ext_vector_type(8)));
typedef float f32x4  __attribute__((ext_vector_type(4)));

__device__ __forceinline__ unsigned short f2bf(float f) {
  union { float f; unsigned int u; } v; v.f = f;
  return (unsigned short)((v.u + 0x7FFFu + ((v.u >> 16) & 1u)) >> 16);
}

// q[b][p] = (h[b,i0,:] + h[b,i1,:]) . W[p,:]   (exact fp32)
__global__ __launch_bounds__(64) void qk_kernel(const float* __restrict__ h,
                                                const int* __restrict__ ids,
                                                const float* __restrict__ W,
                                                float* __restrict__ q) {
  int b = blockIdx.x, p = blockIdx.y;
  int lane = threadIdx.x;
  int i0 = ids[b * 2 + 0], i1 = ids[b * 2 + 1];
  const float* r0 = h + ((size_t)b * SEQ + i0) * HID;
  const float* r1 = h + ((size_t)b * SEQ + i1) * HID;
  const float* w  = W + (size_t)p * HID;
  float acc = 0.f;
  #pragma unroll
  for (int j = 0; j < HID / 64; ++j) {
    int k = lane + j * 64;
    acc += (r0[k] + r1[k]) * w[k];
  }
  #pragma unroll
  for (int off = 32; off > 0; off >>= 1)
    acc += __shfl_down(acc, off, 64);
  if (lane == 0) q[b * P2 + p] = acc;
}

__global__ __launch_bounds__(BLK) void gemm_kernel(const float* __restrict__ h,
                                                   const int* __restrict__ mask,
                                                   const float* __restrict__ W,
                                                   const float* __restrict__ bias,
                                                   const float* __restrict__ q,
                                                   float* __restrict__ out) {
  // W half-tile resident in LDS: rows 0..45 real, 46..47 zero. 48*392*2 = 37632 B.
  __shared__ __align__(16) unsigned short wlds[48 * WST];

  const int tid  = threadIdx.x;
  const int lane = tid & 63, wv = tid >> 6;
  const int mr   = lane & 15, qd = lane >> 4;
  const int row0 = blockIdx.x * 64;              // block covers 64 rows (flat b*512+s)
  const int b    = row0 >> 9;
  const int rowa = row0 + (wv << 4) + mr;        // this lane's A-row
  const float* hrow = h + (size_t)rowa * HID + (qd << 3);

  f32x4 acc[3];
  #pragma unroll
  for (int nt = 0; nt < 3; ++nt) acc[nt] = f32x4{0.f, 0.f, 0.f, 0.f};

  auto stageW = [&](int half) {
    // rows 46,47: zero (covers full padded span of both rows)
    for (int i = tid; i < (2 * WST) / 2; i += BLK)
      ((unsigned int*)(wlds + 46 * WST))[i] = 0u;
    // rows 0..45, cols 0..383 of this K-half
    for (int i = tid; i < (P2 * KH) / 4; i += BLK) {
      int f = i * 4;
      int r = f / KH;
      int c = f - r * KH;
      float4 w4 = *(const float4*)(W + (size_t)r * HID + half * KH + c);
      ushort4 v;
      v.x = f2bf(w4.x); v.y = f2bf(w4.y); v.z = f2bf(w4.z); v.w = f2bf(w4.w);
      *(ushort4*)&wlds[r * WST + c] = v;
    }
  };

  auto phase = [&](int half) {
    const float* hb = hrow + half * KH;
    // Issue ALL A-loads for this half upfront: 24 float4 in flight per lane-pair group.
    float4 abuf[24];
    #pragma unroll
    for (int i = 0; i < 24; ++i)
      abuf[i] = *(const float4*)(hb + (i >> 1) * 32 + (i & 1) * 4);
    #pragma unroll
    for (int it = 0; it < 12; ++it) {
      bf16x8 a;
      {
        float4 x0 = abuf[2 * it], x1 = abuf[2 * it + 1];
        a[0] = (short)f2bf(x0.x); a[1] = (short)f2bf(x0.y);
        a[2] = (short)f2bf(x0.z); a[3] = (short)f2bf(x0.w);
        a[4] = (short)f2bf(x1.x); a[5] = (short)f2bf(x1.y);
        a[6] = (short)f2bf(x1.z); a[7] = (short)f2bf(x1.w);
      }
      #pragma unroll
      for (int nt = 0; nt < 3; ++nt) {
        bf16x8 bb = *(const bf16x8*)&wlds[((nt << 4) + mr) * WST + it * 32 + (qd << 3)];
        acc[nt] = __builtin_amdgcn_mfma_f32_16x16x32_bf16(a, bb, acc[nt], 0, 0, 0);
      }
    }
  };

  stageW(0);
  __syncthreads();
  phase(0);
  __syncthreads();
  stageW(1);
  __syncthreads();
  phase(1);

  // epilogue: C/D layout col = lane&15, row = quad*4 + reg
  int mrow[4];
  #pragma unroll
  for (int i = 0; i < 4; ++i)
    mrow[i] = mask[row0 + (wv << 4) + (qd << 2) + i];

  #pragma unroll
  for (int nt = 0; nt < 3; ++nt) {
    int p = (nt << 4) + mr;
    if (p < P2) {
      float bv = bias[p];
      float qv = q[b * P2 + p];
      #pragma unroll
      for (int i = 0; i < 4; ++i) {
        int row = row0 + (wv << 4) + (qd << 2) + i;
        float x = acc[nt][i] + bv + (mrow[i] ? qv : 0.f);
        float sg = 1.f / (1.f + __expf(-x));
        sg *= sg; sg *= sg;               // sigmoid^4
        out[(size_t)row * P2 + p] = sg;
      }
    }
  }
}

extern "C" void kernel_launch(void* const* d_in, const int* in_sizes, int n_in,
                              void* d_out, int out_size, void* d_ws, size_t ws_size,
                              hipStream_t stream) {
  const float* h    = (const float*)d_in[0];   // [64,512,768] fp32
  const int*   ids  = (const int*)d_in[1];     // [64,2]
  const int*   mask = (const int*)d_in[2];     // [64,512]
  const float* W    = (const float*)d_in[3];   // [46,768]
  const float* bias = (const float*)d_in[4];   // [46]
  float* out = (float*)d_out;                  // [64,512,46] fp32
  float* q   = (float*)d_ws;                   // [64,46] fp32 scratch

  qk_kernel<<<dim3(64, P2), 64, 0, stream>>>(h, ids, W, q);
  gemm_kernel<<<dim3((64 * SEQ) / 64), BLK, 0, stream>>>(h, mask, W, bias, q, out);
}